// Round 5
// baseline (151.934 us; speedup 1.0000x reference)
//
#include <hip/hip_runtime.h>
#include <hip/hip_bf16.h>

#define TT 512
#define HH 1024
#define EE 32
#define KK 4
#define II 512
#define SS 2048

using f32x4 = __attribute__((ext_vector_type(4))) float;
using s16x8 = __attribute__((ext_vector_type(8))) short;

__device__ __forceinline__ unsigned short f2bf(float f){
  unsigned int u = __builtin_bit_cast(unsigned int, f);
  u += 0x7fffu + ((u >> 16) & 1u);
  return (unsigned short)(u >> 16);
}

// ---------------- router: logits, top-4, weights, sigmoid gate, x->bf16 -----
__global__ __launch_bounds__(64) void k_router(
    const float* __restrict__ x, const float* __restrict__ Wg,
    unsigned short* __restrict__ xb, int* __restrict__ topk_idx,
    float* __restrict__ topk_w, float* __restrict__ sig_gate){
  int t = blockIdx.x; int l = threadIdx.x;
  const float* xr = x + (size_t)t * HH;
  #pragma unroll
  for(int i=0;i<HH/64;i++){
    int h = l + 64*i;
    xb[(size_t)t*HH + h] = f2bf(xr[h]);
  }
  float acc0=0.f, acc1=0.f, acc2=0.f, acc3=0.f;
  if(l < EE+1){
    const float* wcol = Wg + l;
    for(int h=0; h<HH; h+=4){
      acc0 += xr[h]   * wcol[(size_t)h*(EE+1)];
      acc1 += xr[h+1] * wcol[(size_t)(h+1)*(EE+1)];
      acc2 += xr[h+2] * wcol[(size_t)(h+2)*(EE+1)];
      acc3 += xr[h+3] * wcol[(size_t)(h+3)*(EE+1)];
    }
  }
  __shared__ float lg[EE+1];
  if(l < EE+1) lg[l] = (acc0+acc1)+(acc2+acc3);
  __syncthreads();
  if(l == 0){
    float v[EE];
    #pragma unroll
    for(int i=0;i<EE;i++) v[i]=lg[i];
    int idx[KK]; float val[KK];
    #pragma unroll
    for(int k=0;k<KK;k++){
      float m=-1e30f; int mi=0;
      for(int i=0;i<EE;i++){ if(v[i]>m){ m=v[i]; mi=i; } }
      idx[k]=mi; val[k]=m; v[mi]=-1e30f;
    }
    float mx = val[0], s=0.f; float w[KK];
    #pragma unroll
    for(int k=0;k<KK;k++){ w[k]=__expf(val[k]-mx); s+=w[k]; }
    float inv = 1.f/s;
    #pragma unroll
    for(int k=0;k<KK;k++){ topk_idx[t*KK+k]=idx[k]; topk_w[t*KK+k]=w[k]*inv; }
    sig_gate[t] = 1.f/(1.f+__expf(-lg[EE]));
  }
}

// ---------------- per-expert token list (deterministic compaction) ----------
__global__ __launch_bounds__(64) void k_build(
    const int* __restrict__ topk_idx, const float* __restrict__ topk_w,
    int* __restrict__ token_list, float* __restrict__ weight_list,
    int* __restrict__ counts){
  int e = blockIdx.x; int l = threadIdx.x;
  int cnt = 0;
  for(int c=0;c<TT;c+=64){
    int t = c + l;
    int kk = -1;
    #pragma unroll
    for(int k=0;k<KK;k++) if(topk_idx[t*KK+k]==e) kk=k;
    unsigned long long b = __ballot(kk>=0);
    int pre = __popcll(b & ((1ull<<l)-1ull));
    if(kk>=0){
      token_list[e*TT + cnt + pre] = t;
      weight_list[e*TT + cnt + pre] = topk_w[t*KK+kk];
    }
    cnt += __popcll(b);
  }
  if(l==0) counts[e]=cnt;
}

// ---- B LDS store: thread holds rows krow,krow+1 x cols nb..nb+3 (float4 x2).
// Writes 4 uints: Bs[nb+j][krow..krow+1] as packed bf16 pair. Pitch 40 ushorts.
__device__ __forceinline__ void stB(unsigned short* B, int nb, int krow,
                                    float4 r0, float4 r1){
  const float* a = (const float*)&r0;
  const float* b = (const float*)&r1;
  #pragma unroll
  for(int j=0;j<4;j++){
    unsigned v = (unsigned)f2bf(a[j]) | ((unsigned)f2bf(b[j]) << 16);
    *reinterpret_cast<unsigned*>(B + (size_t)(nb+j)*40 + krow) = v;
  }
}

// ============ core GEMM: C(64 x 64) += A(64 x K) * B(K x 64), K-step 32 =====
// DUAL: two B matrices sharing the A tile.
// A thread role: ar=tid>>2 (row), as_=tid&3 (16B seg); 1 dwordx4/step.
// B thread role: krow=2*(tid>>4), nb=4*(tid&15); 2 dwordx4 per B per step.
// Gp/Up are pre-offset by column (n0+nb); row*ldb added here.
template<bool DUAL>
__device__ __forceinline__ void gemm64(
    const unsigned short* A0, bool va,
    const float* Gp, const float* Up, int ldb, int NK,
    f32x4* ag, f32x4* au,
    unsigned short* As, unsigned short* Bg, unsigned short* Bu, int tid){
  const int w = tid>>6, l = tid&63;
  const int ar = tid>>2, as_ = tid&3;
  const int krow = 2*(tid>>4), nb = 4*(tid&15);
  const int kt = l>>4, mm = l&15;
  uint4 av = va ? *reinterpret_cast<const uint4*>(A0) : make_uint4(0,0,0,0);
  float4 g0 = *reinterpret_cast<const float4*>(Gp + (size_t)krow*ldb);
  float4 g1 = *reinterpret_cast<const float4*>(Gp + (size_t)(krow+1)*ldb);
  float4 u0, u1;
  if(DUAL){
    u0 = *reinterpret_cast<const float4*>(Up + (size_t)krow*ldb);
    u1 = *reinterpret_cast<const float4*>(Up + (size_t)(krow+1)*ldb);
  }
  *reinterpret_cast<uint4*>(As + (size_t)ar*40 + as_*8) = av;
  stB(Bg, nb, krow, g0, g1);
  if(DUAL) stB(Bu, nb, krow, u0, u1);
  __syncthreads();
  for(int ks=0; ks<NK; ks++){
    const int cur = ks & 1;
    const bool more = (ks+1 < NK);
    if(more){
      av = va ? *reinterpret_cast<const uint4*>(A0 + (size_t)(ks+1)*32)
              : make_uint4(0,0,0,0);
      const float* gb = Gp + (size_t)(ks+1)*32*ldb;
      g0 = *reinterpret_cast<const float4*>(gb + (size_t)krow*ldb);
      g1 = *reinterpret_cast<const float4*>(gb + (size_t)(krow+1)*ldb);
      if(DUAL){
        const float* ub = Up + (size_t)(ks+1)*32*ldb;
        u0 = *reinterpret_cast<const float4*>(ub + (size_t)krow*ldb);
        u1 = *reinterpret_cast<const float4*>(ub + (size_t)(krow+1)*ldb);
      }
    }
    s16x8 bg_[4], bu_[4];
    #pragma unroll
    for(int c=0;c<4;c++){
      bg_[c] = *reinterpret_cast<const s16x8*>(Bg + ((size_t)cur*64 + c*16 + mm)*40 + kt*8);
      if(DUAL)
        bu_[c] = *reinterpret_cast<const s16x8*>(Bu + ((size_t)cur*64 + c*16 + mm)*40 + kt*8);
    }
    s16x8 af = *reinterpret_cast<const s16x8*>(As + ((size_t)cur*64 + w*16 + mm)*40 + kt*8);
    #pragma unroll
    for(int c=0;c<4;c++){
      ag[c] = __builtin_amdgcn_mfma_f32_16x16x32_bf16(af, bg_[c], ag[c], 0,0,0);
      if(DUAL)
        au[c] = __builtin_amdgcn_mfma_f32_16x16x32_bf16(af, bu_[c], au[c], 0,0,0);
    }
    if(more){
      const int nx = cur^1;
      *reinterpret_cast<uint4*>(As + ((size_t)nx*64 + ar)*40 + as_*8) = av;
      stB(Bg + (size_t)nx*64*40, nb, krow, g0, g1);
      if(DUAL) stB(Bu + (size_t)nx*64*40, nb, krow, u0, u1);
    }
    __syncthreads();
  }
}

// ---------------- phase 2: ALL gate-up (shared + routed), 64x64 tiles -------
__global__ __launch_bounds__(256) void k_gateup_all(
    const unsigned short* __restrict__ xb,
    const float* __restrict__ Wsg, const float* __restrict__ Wsu,
    unsigned short* __restrict__ Hs,
    const float* __restrict__ Wgate, const float* __restrict__ Wup,
    const int* __restrict__ token_list, const int* __restrict__ counts,
    unsigned short* __restrict__ hbuf){
  __shared__ unsigned short As[2*64*40];   // 10.25 KB
  __shared__ unsigned short Bg[2*64*40];
  __shared__ unsigned short Bu[2*64*40];
  int tid = threadIdx.x, w = tid>>6, l = tid&63;
  int ar = tid>>2, as_ = tid&3, nb = 4*(tid&15);
  int bid = blockIdx.x;
  f32x4 zero = {0.f,0.f,0.f,0.f};
  const int NSH = (TT/64)*(SS/64);   // 8*32 = 256

  if(bid < NSH){
    int n0 = (bid & 31) * 64;
    int r0 = (bid >> 5) * 64;
    f32x4 ag[4]={zero,zero,zero,zero}, au[4]={zero,zero,zero,zero};
    const unsigned short* A0 = xb + (size_t)(r0+ar)*HH + as_*8;
    const float* Gp = Wsg + n0 + nb;
    const float* Up = Wsu + n0 + nb;
    gemm64<true>(A0, true, Gp, Up, SS, HH/32, ag, au, As, Bg, Bu, tid);
    int mm = l&15, rb = r0 + w*16 + (l>>4)*4;
    #pragma unroll
    for(int c=0;c<4;c++){
      #pragma unroll
      for(int j=0;j<4;j++){
        float g = ag[c][j], u = au[c][j];
        Hs[(size_t)(rb+j)*SS + n0 + c*16 + mm] = f2bf(g*u/(1.f+__expf(-g)));
      }
    }
  } else {
    int b = bid - NSH;
    int e = b >> 3;            // II/64 = 8 tiles per expert
    int i0 = (b & 7) * 64;
    int cnt = counts[e]; if(cnt == 0) return;
    int off = 0;
    for(int i=0;i<e;i++) off += counts[i];
    const float* Gp0 = Wgate + (size_t)e*HH*II + i0 + nb;
    const float* Up0 = Wup   + (size_t)e*HH*II + i0 + nb;
    for(int rt=0; rt*64<cnt; rt++){
      int nv = cnt - rt*64; if(nv > 64) nv = 64;
      const int* rows = token_list + e*TT + rt*64;
      int arow = (ar < nv) ? rows[ar] : 0;
      bool va = ar < nv;
      f32x4 ag[4]={zero,zero,zero,zero}, au[4]={zero,zero,zero,zero};
      const unsigned short* A0 = xb + (size_t)arow*HH + as_*8;
      gemm64<true>(A0, va, Gp0, Up0, II, HH/32, ag, au, As, Bg, Bu, tid);
      int mm = l&15, rr0 = w*16 + (l>>4)*4;
      #pragma unroll
      for(int c=0;c<4;c++){
        #pragma unroll
        for(int j=0;j<4;j++){
          int rr = rr0 + j;
          if(rr < nv){
            float g = ag[c][j], u = au[c][j];
            hbuf[(size_t)(off+rt*64+rr)*II + i0 + c*16 + mm] =
                f2bf(g*u/(1.f+__expf(-g)));
          }
        }
      }
    }
  }
}

// ---------------- phase 3: ALL down (shared + routed), 64x64 tiles ----------
__global__ __launch_bounds__(256) void k_down_all(
    const unsigned short* __restrict__ Hsrc, const float* __restrict__ Wsd,
    const float* __restrict__ sig_gate,
    const unsigned short* __restrict__ hbuf, const float* __restrict__ Wdown,
    const int* __restrict__ token_list, const float* __restrict__ weight_list,
    const int* __restrict__ counts, float* __restrict__ out){
  __shared__ unsigned short As[2*64*40];
  __shared__ unsigned short Bs[2*64*40];
  int tid = threadIdx.x, w = tid>>6, l = tid&63;
  int ar = tid>>2, as_ = tid&3, nb = 4*(tid&15);
  int bid = blockIdx.x;
  f32x4 zero = {0.f,0.f,0.f,0.f};
  const int NSH = (TT/64)*(HH/64);   // 8*16 = 128

  if(bid < NSH){
    int n0 = (bid & 15) * 64;
    int r0 = (bid >> 4) * 64;
    f32x4 acc[4]={zero,zero,zero,zero};
    const unsigned short* A0 = Hsrc + (size_t)(r0+ar)*SS + as_*8;
    const float* Bp = Wsd + n0 + nb;
    gemm64<false>(A0, true, Bp, Bp, HH, SS/32, acc, acc, As, Bs, Bs, tid);
    int mm = l&15, rb = r0 + w*16 + (l>>4)*4;
    #pragma unroll
    for(int c=0;c<4;c++){
      #pragma unroll
      for(int j=0;j<4;j++){
        atomicAdd(&out[(size_t)(rb+j)*HH + n0 + c*16 + mm],
                  sig_gate[rb+j]*acc[c][j]);
      }
    }
  } else {
    int b = bid - NSH;
    int e = b >> 4;            // HH/64 = 16 tiles per expert
    int n0 = (b & 15) * 64;
    int cnt = counts[e]; if(cnt == 0) return;
    int off = 0;
    for(int i=0;i<e;i++) off += counts[i];
    const float* Bp = Wdown + (size_t)e*II*HH + n0 + nb;
    for(int rt=0; rt*64<cnt; rt++){
      int nv = cnt - rt*64; if(nv > 64) nv = 64;
      bool va = ar < nv;
      f32x4 acc[4]={zero,zero,zero,zero};
      const unsigned short* A0 = hbuf + (size_t)(off+rt*64+ar)*II + as_*8;
      gemm64<false>(A0, va, Bp, Bp, HH, II/32, acc, acc, As, Bs, Bs, tid);
      int mm = l&15, rr0 = w*16 + (l>>4)*4;
      #pragma unroll
      for(int c=0;c<4;c++){
        #pragma unroll
        for(int j=0;j<4;j++){
          int rr = rr0 + j;
          if(rr < nv){
            int t = token_list[e*TT + rt*64 + rr];
            float wt = weight_list[e*TT + rt*64 + rr];
            atomicAdd(&out[(size_t)t*HH + n0 + c*16 + mm], wt*acc[c][j]);
          }
        }
      }
    }
  }
}

extern "C" void kernel_launch(void* const* d_in, const int* in_sizes, int n_in,
                              void* d_out, int out_size, void* d_ws, size_t ws_size,
                              hipStream_t stream) {
  const float* x     = (const float*)d_in[0];
  const float* Wg    = (const float*)d_in[1];
  const float* Wgate = (const float*)d_in[2];
  const float* Wup   = (const float*)d_in[3];
  const float* Wdown = (const float*)d_in[4];
  const float* Wsg   = (const float*)d_in[5];
  const float* Wsu   = (const float*)d_in[6];
  const float* Wsd   = (const float*)d_in[7];
  float* out = (float*)d_out;

  char* ws = (char*)d_ws;
  unsigned short* xb   = (unsigned short*)ws; ws += (size_t)TT*HH*2;
  unsigned short* Hs   = (unsigned short*)ws; ws += (size_t)TT*SS*2;
  unsigned short* hbuf = (unsigned short*)ws; ws += (size_t)(TT*KK+64)*II*2;
  int*   token_list  = (int*)ws;   ws += (size_t)EE*TT*4;
  float* weight_list = (float*)ws; ws += (size_t)EE*TT*4;
  int*   topk_idx    = (int*)ws;   ws += (size_t)TT*KK*4;
  float* topk_wq     = (float*)ws; ws += (size_t)TT*KK*4;
  int*   counts      = (int*)ws;   ws += 128;
  float* sig_gate    = (float*)ws; ws += (size_t)TT*4;

  hipMemsetAsync(d_out, 0, (size_t)TT*HH*4, stream);
  k_router<<<TT, 64, 0, stream>>>(x, Wg, xb, topk_idx, topk_wq, sig_gate);
  k_build<<<EE, 64, 0, stream>>>(topk_idx, topk_wq, token_list, weight_list, counts);
  k_gateup_all<<<(TT/64)*(SS/64) + EE*(II/64), 256, 0, stream>>>(
      xb, Wsg, Wsu, Hs, Wgate, Wup, token_list, counts, hbuf);
  k_down_all<<<(TT/64)*(HH/64) + EE*(HH/64), 256, 0, stream>>>(
      Hs, Wsd, sig_gate, hbuf, Wdown, token_list, weight_list, counts, out);
}

// Round 6
// 151.185 us; speedup vs baseline: 1.0050x; 1.0050x over previous
//
#include <hip/hip_runtime.h>
#include <hip/hip_bf16.h>

#define TT 512
#define HH 1024
#define EE 32
#define KK 4
#define II 512
#define SS 2048

using f32x4 = __attribute__((ext_vector_type(4))) float;
using s16x8 = __attribute__((ext_vector_type(8))) short;
using u32x4 = __attribute__((ext_vector_type(4))) unsigned;

__device__ __forceinline__ unsigned short f2bf(float f){
  unsigned int u = __builtin_bit_cast(unsigned int, f);
  u += 0x7fffu + ((u >> 16) & 1u);
  return (unsigned short)(u >> 16);
}
__device__ __forceinline__ unsigned pk2(float a, float b){
  return (unsigned)f2bf(a) | ((unsigned)f2bf(b) << 16);
}
__device__ __forceinline__ void barrier_lds(){
  asm volatile("s_waitcnt lgkmcnt(0)" ::: "memory");
  __builtin_amdgcn_s_barrier();
}

// ---------------- router: logits, top-4, weights, sigmoid gate, x->bf16 -----
__global__ __launch_bounds__(64) void k_router(
    const float* __restrict__ x, const float* __restrict__ Wg,
    unsigned short* __restrict__ xb, int* __restrict__ topk_idx,
    float* __restrict__ topk_w, float* __restrict__ sig_gate){
  int t = blockIdx.x; int l = threadIdx.x;
  const float* xr = x + (size_t)t * HH;
  #pragma unroll
  for(int i=0;i<HH/64;i++){
    int h = l + 64*i;
    xb[(size_t)t*HH + h] = f2bf(xr[h]);
  }
  float acc0=0.f, acc1=0.f, acc2=0.f, acc3=0.f;
  if(l < EE+1){
    const float* wcol = Wg + l;
    for(int h=0; h<HH; h+=4){
      acc0 += xr[h]   * wcol[(size_t)h*(EE+1)];
      acc1 += xr[h+1] * wcol[(size_t)(h+1)*(EE+1)];
      acc2 += xr[h+2] * wcol[(size_t)(h+2)*(EE+1)];
      acc3 += xr[h+3] * wcol[(size_t)(h+3)*(EE+1)];
    }
  }
  __shared__ float lg[EE+1];
  if(l < EE+1) lg[l] = (acc0+acc1)+(acc2+acc3);
  __syncthreads();
  if(l == 0){
    float v[EE];
    #pragma unroll
    for(int i=0;i<EE;i++) v[i]=lg[i];
    int idx[KK]; float val[KK];
    #pragma unroll
    for(int k=0;k<KK;k++){
      float m=-1e30f; int mi=0;
      for(int i=0;i<EE;i++){ if(v[i]>m){ m=v[i]; mi=i; } }
      idx[k]=mi; val[k]=m; v[mi]=-1e30f;
    }
    float mx = val[0], s=0.f; float w[KK];
    #pragma unroll
    for(int k=0;k<KK;k++){ w[k]=__expf(val[k]-mx); s+=w[k]; }
    float inv = 1.f/s;
    #pragma unroll
    for(int k=0;k<KK;k++){ topk_idx[t*KK+k]=idx[k]; topk_w[t*KK+k]=w[k]*inv; }
    sig_gate[t] = 1.f/(1.f+__expf(-lg[EE]));
  }
}

// ---------------- per-expert token list (deterministic compaction) ----------
__global__ __launch_bounds__(64) void k_build(
    const int* __restrict__ topk_idx, const float* __restrict__ topk_w,
    int* __restrict__ token_list, float* __restrict__ weight_list,
    int* __restrict__ counts){
  int e = blockIdx.x; int l = threadIdx.x;
  int cnt = 0;
  for(int c=0;c<TT;c+=64){
    int t = c + l;
    int kk = -1;
    #pragma unroll
    for(int k=0;k<KK;k++) if(topk_idx[t*KK+k]==e) kk=k;
    unsigned long long b = __ballot(kk>=0);
    int pre = __popcll(b & ((1ull<<l)-1ull));
    if(kk>=0){
      token_list[e*TT + cnt + pre] = t;
      weight_list[e*TT + cnt + pre] = topk_w[t*KK+kk];
    }
    cnt += __popcll(b);
  }
  if(l==0) counts[e]=cnt;
}

// ============ core GEMM: C(64 x 64) += A(64 x K) * B(K x 64), K-step 32 =====
// Depth-2 register pipeline, raw s_barrier (counted vmcnt), swizzled B LDS.
// A LDS: [h][64 rows][40 ushorts] (pitch 80 B, b128 ops, ~2-way).
// B LDS: [h][16 kp][64 dwords]; dword (kp,n) = bf16 pair (k=2kp,2kp+1) of col n,
//        column index swizzled: n ^ (((kp>>2)&3)<<3)  -> 2-way reads/writes.
// A role: ar=tid>>2 row, as_=tid&3 16B seg. B role: cols 4*(tid&15), kp=tid>>4.
template<bool DUAL>
__device__ __forceinline__ void gemm64(
    const unsigned short* __restrict__ A0, bool va,
    const float* __restrict__ Gp, const float* __restrict__ Up,
    int ldb, int NK,
    f32x4* ag, f32x4* au,
    unsigned short* As, unsigned* Bg, unsigned* Bu, int tid){
  const int w = tid>>6, l = tid&63;
  const int ar = tid>>2, as_ = tid&3;
  const int m16 = tid&15, g2 = tid>>4;
  const int krow = 2*g2;
  const int kt = l>>4, mm = l&15;
  const unsigned swW = ((unsigned)((g2>>2)&3))<<3;
  const int wB  = g2*64 + ((4*m16) ^ (int)swW);       // B write dword idx
  const int aWr = ar*40 + as_*8;                      // A write ushort idx
  const int aRd = (w*16+mm)*40 + kt*8;                // A read ushort idx
  const unsigned swR = ((unsigned)(kt&3))<<3;         // B read swizzle

  uint4 avA, avB;
  float4 gA0,gA1,uA0,uA1, gB0,gB1,uB0,uB1;

  auto loadBatch = [&](int b, uint4& av, float4& g0, float4& g1,
                       float4& u0, float4& u1){
    av = va ? *reinterpret_cast<const uint4*>(A0 + (size_t)b*32)
            : make_uint4(0,0,0,0);
    const float* p = Gp + (size_t)(b*32 + krow)*ldb;
    g0 = *reinterpret_cast<const float4*>(p);
    g1 = *reinterpret_cast<const float4*>(p + ldb);
    if(DUAL){
      const float* q = Up + (size_t)(b*32 + krow)*ldb;
      u0 = *reinterpret_cast<const float4*>(q);
      u1 = *reinterpret_cast<const float4*>(q + ldb);
    }
  };
  auto storeBatch = [&](int h, uint4 av, float4 g0, float4 g1,
                        float4 u0, float4 u1){
    *reinterpret_cast<uint4*>(As + (size_t)h*64*40 + aWr) = av;
    u32x4 vg; vg.x=pk2(g0.x,g1.x); vg.y=pk2(g0.y,g1.y);
    vg.z=pk2(g0.z,g1.z); vg.w=pk2(g0.w,g1.w);
    *reinterpret_cast<u32x4*>(Bg + (size_t)h*16*64 + wB) = vg;
    if(DUAL){
      u32x4 vu; vu.x=pk2(u0.x,u1.x); vu.y=pk2(u0.y,u1.y);
      vu.z=pk2(u0.z,u1.z); vu.w=pk2(u0.w,u1.w);
      *reinterpret_cast<u32x4*>(Bu + (size_t)h*16*64 + wB) = vu;
    }
  };
  auto compute = [&](int h){
    const unsigned* Bgh = Bg + (size_t)h*16*64;
    const unsigned* Buh = Bu + (size_t)h*16*64;
    s16x8 af = *reinterpret_cast<const s16x8*>(As + (size_t)h*64*40 + aRd);
    #pragma unroll
    for(int c=0;c<4;c++){
      int base = kt*4*64 + (((c*16+mm)) ^ (int)swR);
      u32x4 tg; tg.x=Bgh[base]; tg.y=Bgh[base+64];
      tg.z=Bgh[base+128]; tg.w=Bgh[base+192];
      s16x8 bg_ = __builtin_bit_cast(s16x8, tg);
      ag[c] = __builtin_amdgcn_mfma_f32_16x16x32_bf16(af, bg_, ag[c], 0,0,0);
      if(DUAL){
        u32x4 tu; tu.x=Buh[base]; tu.y=Buh[base+64];
        tu.z=Buh[base+128]; tu.w=Buh[base+192];
        s16x8 bu_ = __builtin_bit_cast(s16x8, tu);
        au[c] = __builtin_amdgcn_mfma_f32_16x16x32_bf16(af, bu_, au[c], 0,0,0);
      }
    }
  };

  // prologue: batch0 -> LDS[0]; batch1 stays in regs/in-flight
  loadBatch(0, avA, gA0,gA1, uA0,uA1);
  loadBatch(1, avB, gB0,gB1, uB0,uB1);
  storeBatch(0, avA, gA0,gA1, uA0,uA1);
  barrier_lds();
  for(int ks=0; ks<NK; ks+=2){
    const bool m2 = (ks+2 < NK), m3 = (ks+3 < NK);
    if(m2) loadBatch(ks+2, avA, gA0,gA1, uA0,uA1);
    compute(0);
    storeBatch(1, avB, gB0,gB1, uB0,uB1);   // waits only batch ks+1 loads
    barrier_lds();
    if(m3) loadBatch(ks+3, avB, gB0,gB1, uB0,uB1);
    compute(1);
    if(m2) storeBatch(0, avA, gA0,gA1, uA0,uA1);
    barrier_lds();
  }
}

// ---------------- phase 2: ALL gate-up (shared + routed), 64x64 tiles -------
__global__ __launch_bounds__(256) void k_gateup_all(
    const unsigned short* __restrict__ xb,
    const float* __restrict__ Wsg, const float* __restrict__ Wsu,
    unsigned short* __restrict__ Hs,
    const float* __restrict__ Wgate, const float* __restrict__ Wup,
    const int* __restrict__ token_list, const int* __restrict__ counts,
    unsigned short* __restrict__ hbuf){
  __shared__ __align__(16) unsigned short As[2*64*40];
  __shared__ __align__(16) unsigned Bg[2*16*64];
  __shared__ __align__(16) unsigned Bu[2*16*64];
  int tid = threadIdx.x, w = tid>>6, l = tid&63;
  int ar = tid>>2, as_ = tid&3, m16 = tid&15;
  int bid = blockIdx.x;
  f32x4 zero = {0.f,0.f,0.f,0.f};
  const int NSH = (TT/64)*(SS/64);   // 256

  if(bid < NSH){
    int n0 = (bid & 31) * 64;
    int r0 = (bid >> 5) * 64;
    f32x4 ag[4]={zero,zero,zero,zero}, au[4]={zero,zero,zero,zero};
    const unsigned short* A0 = xb + (size_t)(r0+ar)*HH + as_*8;
    const float* Gp = Wsg + n0 + 4*m16;
    const float* Up = Wsu + n0 + 4*m16;
    gemm64<true>(A0, true, Gp, Up, SS, HH/32, ag, au, As, Bg, Bu, tid);
    int mm = l&15, rb = r0 + w*16 + (l>>4)*4;
    #pragma unroll
    for(int c=0;c<4;c++){
      #pragma unroll
      for(int j=0;j<4;j++){
        float g = ag[c][j], u = au[c][j];
        Hs[(size_t)(rb+j)*SS + n0 + c*16 + mm] = f2bf(g*u/(1.f+__expf(-g)));
      }
    }
  } else {
    int b = bid - NSH;
    int e = b >> 3;            // II/64 = 8 tiles per expert
    int i0 = (b & 7) * 64;
    int cnt = counts[e]; if(cnt == 0) return;
    int off = 0;
    for(int i=0;i<e;i++) off += counts[i];
    const float* Gp0 = Wgate + (size_t)e*HH*II + i0 + 4*m16;
    const float* Up0 = Wup   + (size_t)e*HH*II + i0 + 4*m16;
    for(int rt=0; rt*64<cnt; rt++){
      int nv = cnt - rt*64; if(nv > 64) nv = 64;
      const int* rows = token_list + e*TT + rt*64;
      int arow = (ar < nv) ? rows[ar] : 0;
      bool va = ar < nv;
      f32x4 ag[4]={zero,zero,zero,zero}, au[4]={zero,zero,zero,zero};
      const unsigned short* A0 = xb + (size_t)arow*HH + as_*8;
      gemm64<true>(A0, va, Gp0, Up0, II, HH/32, ag, au, As, Bg, Bu, tid);
      int mm = l&15, rr0 = w*16 + (l>>4)*4;
      #pragma unroll
      for(int c=0;c<4;c++){
        #pragma unroll
        for(int j=0;j<4;j++){
          int rr = rr0 + j;
          if(rr < nv){
            float g = ag[c][j], u = au[c][j];
            hbuf[(size_t)(off+rt*64+rr)*II + i0 + c*16 + mm] =
                f2bf(g*u/(1.f+__expf(-g)));
          }
        }
      }
    }
  }
}

// ---------------- phase 3: ALL down (shared + routed), 64x64 tiles ----------
__global__ __launch_bounds__(256) void k_down_all(
    const unsigned short* __restrict__ Hsrc, const float* __restrict__ Wsd,
    const float* __restrict__ sig_gate,
    const unsigned short* __restrict__ hbuf, const float* __restrict__ Wdown,
    const int* __restrict__ token_list, const float* __restrict__ weight_list,
    const int* __restrict__ counts, float* __restrict__ out){
  __shared__ __align__(16) unsigned short As[2*64*40];
  __shared__ __align__(16) unsigned Bs[2*16*64];
  int tid = threadIdx.x, w = tid>>6, l = tid&63;
  int ar = tid>>2, as_ = tid&3, m16 = tid&15;
  int bid = blockIdx.x;
  f32x4 zero = {0.f,0.f,0.f,0.f};
  const int NSH = (TT/64)*(HH/64);   // 128

  if(bid < NSH){
    int n0 = (bid & 15) * 64;
    int r0 = (bid >> 4) * 64;
    f32x4 acc[4]={zero,zero,zero,zero};
    const unsigned short* A0 = Hsrc + (size_t)(r0+ar)*SS + as_*8;
    const float* Bp = Wsd + n0 + 4*m16;
    gemm64<false>(A0, true, Bp, Bp, HH, SS/32, acc, acc, As, Bs, Bs, tid);
    int mm = l&15, rb = r0 + w*16 + (l>>4)*4;
    #pragma unroll
    for(int c=0;c<4;c++){
      #pragma unroll
      for(int j=0;j<4;j++){
        atomicAdd(&out[(size_t)(rb+j)*HH + n0 + c*16 + mm],
                  sig_gate[rb+j]*acc[c][j]);
      }
    }
  } else {
    int b = bid - NSH;
    int e = b >> 4;            // HH/64 = 16 tiles per expert
    int n0 = (b & 15) * 64;
    int cnt = counts[e]; if(cnt == 0) return;
    int off = 0;
    for(int i=0;i<e;i++) off += counts[i];
    const float* Bp = Wdown + (size_t)e*II*HH + n0 + 4*m16;
    for(int rt=0; rt*64<cnt; rt++){
      int nv = cnt - rt*64; if(nv > 64) nv = 64;
      bool va = ar < nv;
      f32x4 acc[4]={zero,zero,zero,zero};
      const unsigned short* A0 = hbuf + (size_t)(off+rt*64+ar)*II + as_*8;
      gemm64<false>(A0, va, Bp, Bp, HH, II/32, acc, acc, As, Bs, Bs, tid);
      int mm = l&15, rr0 = w*16 + (l>>4)*4;
      #pragma unroll
      for(int c=0;c<4;c++){
        #pragma unroll
        for(int j=0;j<4;j++){
          int rr = rr0 + j;
          if(rr < nv){
            int t = token_list[e*TT + rt*64 + rr];
            float wt = weight_list[e*TT + rt*64 + rr];
            atomicAdd(&out[(size_t)t*HH + n0 + c*16 + mm], wt*acc[c][j]);
          }
        }
      }
    }
  }
}

extern "C" void kernel_launch(void* const* d_in, const int* in_sizes, int n_in,
                              void* d_out, int out_size, void* d_ws, size_t ws_size,
                              hipStream_t stream) {
  const float* x     = (const float*)d_in[0];
  const float* Wg    = (const float*)d_in[1];
  const float* Wgate = (const float*)d_in[2];
  const float* Wup   = (const float*)d_in[3];
  const float* Wdown = (const float*)d_in[4];
  const float* Wsg   = (const float*)d_in[5];
  const float* Wsu   = (const float*)d_in[6];
  const float* Wsd   = (const float*)d_in[7];
  float* out = (float*)d_out;

  char* ws = (char*)d_ws;
  unsigned short* xb   = (unsigned short*)ws; ws += (size_t)TT*HH*2;
  unsigned short* Hs   = (unsigned short*)ws; ws += (size_t)TT*SS*2;
  unsigned short* hbuf = (unsigned short*)ws; ws += (size_t)(TT*KK+64)*II*2;
  int*   token_list  = (int*)ws;   ws += (size_t)EE*TT*4;
  float* weight_list = (float*)ws; ws += (size_t)EE*TT*4;
  int*   topk_idx    = (int*)ws;   ws += (size_t)TT*KK*4;
  float* topk_wq     = (float*)ws; ws += (size_t)TT*KK*4;
  int*   counts      = (int*)ws;   ws += 128;
  float* sig_gate    = (float*)ws; ws += (size_t)TT*4;

  hipMemsetAsync(d_out, 0, (size_t)TT*HH*4, stream);
  k_router<<<TT, 64, 0, stream>>>(x, Wg, xb, topk_idx, topk_wq, sig_gate);
  k_build<<<EE, 64, 0, stream>>>(topk_idx, topk_wq, token_list, weight_list, counts);
  k_gateup_all<<<(TT/64)*(SS/64) + EE*(II/64), 256, 0, stream>>>(
      xb, Wsg, Wsu, Hs, Wgate, Wup, token_list, counts, hbuf);
  k_down_all<<<(TT/64)*(HH/64) + EE*(HH/64), 256, 0, stream>>>(
      Hs, Wsd, sig_gate, hbuf, Wdown, token_list, weight_list, counts, out);
}